// Round 16
// baseline (262.600 us; speedup 1.0000x reference)
//
#include <hip/hip_runtime.h>
#include <hip/hip_fp16.h>

#define N_NODES 100000
#define N_EDGES 1250000
#define F 64
#define SCAN_CHUNK 1024
#define NBLK_SCAN ((N_NODES + SCAN_CHUNK - 1) / SCAN_CHUNK)  // 98
#define NPB 16   // nodes per block: 4 waves x 4 groups(16 lanes) = 16 nodes
#define TP 18    // tile leading pad: keeps (k*TP+n)*4 8B-aligned for float2 reads

// ---------------- CSR-build path ----------------

// K1: histogram of receivers + per-edge rank within receiver.
// The atomic return value IS the rank -> permute needs no atomic at all.
__global__ __launch_bounds__(256) void hist_kernel(const int* __restrict__ ei,
                                                   int* __restrict__ counts,
                                                   int* __restrict__ rank) {
    int e = blockIdx.x * 256 + threadIdx.x;
    if (e < N_EDGES) rank[e] = atomicAdd(&counts[ei[N_EDGES + e]], 1);
}

// K2a: per-1024-chunk partial sums of counts.
__global__ __launch_bounds__(256) void scan_reduce_kernel(const int* __restrict__ counts,
                                                          int* __restrict__ partials) {
    int base = blockIdx.x * SCAN_CHUNK + threadIdx.x * 4;
    int s = 0;
    if (base + 3 < N_NODES) {
        int4 c = *(const int4*)&counts[base];
        s = c.x + c.y + c.z + c.w;
    }
    for (int d = 32; d > 0; d >>= 1) s += __shfl_down(s, d);
    __shared__ int lds[4];
    int lane = threadIdx.x & 63, wave = threadIdx.x >> 6;
    if (lane == 0) lds[wave] = s;
    __syncthreads();
    if (threadIdx.x == 0) partials[blockIdx.x] = lds[0] + lds[1] + lds[2] + lds[3];
}

// K2b: per-chunk exclusive scan; chunk base reduced in-block from raw partials.
__global__ __launch_bounds__(256) void scan_apply_kernel(const int* __restrict__ counts,
                                                         const int* __restrict__ partials,
                                                         int* __restrict__ off) {
    __shared__ int sh_red[4];
    __shared__ int sh_base;
    __shared__ int wsum[4];
    int t = threadIdx.x;
    int lane = t & 63, wave = t >> 6;

    int pp = 0;
    if (t < blockIdx.x && t < NBLK_SCAN) pp = partials[t];
    for (int d = 32; d > 0; d >>= 1) pp += __shfl_down(pp, d);
    if (lane == 0) sh_red[wave] = pp;
    __syncthreads();
    if (t == 0) sh_base = sh_red[0] + sh_red[1] + sh_red[2] + sh_red[3];

    int base = blockIdx.x * SCAN_CHUNK + t * 4;
    int4 c = {0, 0, 0, 0};
    bool act = (base + 3 < N_NODES);
    if (act) c = *(const int4*)&counts[base];
    int s = c.x + c.y + c.z + c.w;

    int xs = s;
    for (int d = 1; d < 64; d <<= 1) {
        int y = __shfl_up(xs, d);
        if (lane >= d) xs += y;
    }
    if (lane == 63) wsum[wave] = xs;
    __syncthreads();
    int pre = xs - s;
    for (int w = 0; w < wave; ++w) pre += wsum[w];
    pre += sh_base;

    if (act) {
        int o0 = pre, o1 = o0 + c.x, o2 = o1 + c.y, o3 = o2 + c.z;
        int4 o = {o0, o1, o2, o3};
        *(int4*)&off[base] = o;
        if (base + 4 == N_NODES) off[N_NODES] = o3 + c.w;  // == N_EDGES
    }
}

// K3: scatter packed payload {src:int, (w0,w1):half2} -> ONE 8B store per edge.
// Atomic-free: pos = off[r] + rank[e].
__global__ __launch_bounds__(256) void permute_kernel(const int* __restrict__ ei,
                                                      const float* __restrict__ ew,
                                                      const int* __restrict__ off,
                                                      const int* __restrict__ rank,
                                                      int2* __restrict__ pay) {
    int e = blockIdx.x * 256 + threadIdx.x;
    if (e >= N_EDGES) return;
    int r = ei[N_EDGES + e];
    int pos = off[r] + rank[e];
    __half2 h = __floats2half2_rn(ew[e], ew[N_EDGES + e]);
    int2 p;
    p.x = ei[e];
    p.y = *(const int*)&h;
    pay[pos] = p;
}

// K3b: x (fp32) -> xh (fp16). Streaming, vectorized. Halves the random-gather
// line count in K4: one 128B line per edge row instead of two.
__global__ __launch_bounds__(256) void cvt_kernel(const float* __restrict__ x,
                                                  __half* __restrict__ xh) {
    int i = blockIdx.x * 256 + threadIdx.x;
    int base = i * 4;
    if (base < N_NODES * F) {
        float4 v = *(const float4*)&x[base];
        __half2 h0 = __floats2half2_rn(v.x, v.y);
        __half2 h1 = __floats2half2_rn(v.z, v.w);
        uint2 u;
        u.x = *(const unsigned int*)&h0;
        u.y = *(const unsigned int*)&h1;
        *(uint2*)&xh[base] = u;
    }
}

// K4: fused aggregation + GEMM. 256 threads = 4 waves x 4 groups of 16 lanes.
// Each 16-lane group owns ONE node; lane l4 holds features [4*l4,4*l4+4).
// fp16 x rows: a group's row read = 16 lanes x 8B = ONE 128B line.
// Pipeline: pay is loaded 2 batches ahead of the x-issue, x 1 batch ahead of
// use -> the pay->x address dependency never stalls an iteration.
// OOB edges in the tail batch are handled by zeroing the weight (loads are
// index-clamped, always valid). GEMM phase: all 256 threads, fp32.
__global__ __launch_bounds__(256, 6) void agg_gemm_kernel(
    const __half* __restrict__ xh, const int* __restrict__ off,
    const int2* __restrict__ pay,
    const float* __restrict__ Wsrc, const float* __restrict__ Wdst,
    const float* __restrict__ bsrc, const float* __restrict__ bdst,
    float* __restrict__ outA, float* __restrict__ outB)
{
    __shared__ float tA[F * TP];
    __shared__ float tB[F * TP];
    int t = threadIdx.x;
    int w = t >> 6;          // wave 0..3
    int lane = t & 63;
    int g = lane >> 4;       // group in wave 0..3
    int l4 = lane & 15;      // feat4 index 0..15
    int nIB = w * 4 + g;     // node in block 0..15
    int n = blockIdx.x * NPB + nIB;

    int beg = off[n];
    int end = off[n + 1];

    float4 accA = {0.f, 0.f, 0.f, 0.f};
    float4 accB = {0.f, 0.f, 0.f, 0.f};

    if (beg < end) {
        int last = end - 1;
        // pay batches A (edges i..i+3) and B (i+4..i+7), x batch for A.
        int2 pa0 = pay[beg];
        int2 pa1 = pay[min(beg + 1, last)];
        int2 pa2 = pay[min(beg + 2, last)];
        int2 pa3 = pay[min(beg + 3, last)];
        int2 pb0 = pay[min(beg + 4, last)];
        int2 pb1 = pay[min(beg + 5, last)];
        int2 pb2 = pay[min(beg + 6, last)];
        int2 pb3 = pay[min(beg + 7, last)];
        uint2 xa0 = *(const uint2*)(xh + (size_t)pa0.x * F + l4 * 4);
        uint2 xa1 = *(const uint2*)(xh + (size_t)pa1.x * F + l4 * 4);
        uint2 xa2 = *(const uint2*)(xh + (size_t)pa2.x * F + l4 * 4);
        uint2 xa3 = *(const uint2*)(xh + (size_t)pa3.x * F + l4 * 4);

        for (int i = beg; i < end; i += 4) {
            // pay batch C (i+8..i+11) -- 2 batches ahead
            int2 pc0 = pay[min(i + 8, last)];
            int2 pc1 = pay[min(i + 9, last)];
            int2 pc2 = pay[min(i + 10, last)];
            int2 pc3 = pay[min(i + 11, last)];
            // x batch B -- addresses from pay loaded last iteration
            uint2 xb0 = *(const uint2*)(xh + (size_t)pb0.x * F + l4 * 4);
            uint2 xb1 = *(const uint2*)(xh + (size_t)pb1.x * F + l4 * 4);
            uint2 xb2 = *(const uint2*)(xh + (size_t)pb2.x * F + l4 * 4);
            uint2 xb3 = *(const uint2*)(xh + (size_t)pb3.x * F + l4 * 4);

            // FMA batch A (x loaded last iteration); zero weight for OOB tail.
#define EDGE(J, PJ, XJ)                                                   \
            {                                                             \
                float2 wv = __half22float2(*(const __half2*)&PJ.y);       \
                if (i + J >= end) { wv.x = 0.f; wv.y = 0.f; }             \
                float2 lo = __half22float2(*(const __half2*)&XJ.x);       \
                float2 hi = __half22float2(*(const __half2*)&XJ.y);       \
                accA.x += lo.x * wv.x; accA.y += lo.y * wv.x;             \
                accA.z += hi.x * wv.x; accA.w += hi.y * wv.x;             \
                accB.x += lo.x * wv.y; accB.y += lo.y * wv.y;             \
                accB.z += hi.x * wv.y; accB.w += hi.y * wv.y;             \
            }
            EDGE(0, pa0, xa0)
            EDGE(1, pa1, xa1)
            EDGE(2, pa2, xa2)
            EDGE(3, pa3, xa3)
#undef EDGE
            // shift pipeline
            pa0 = pb0; pa1 = pb1; pa2 = pb2; pa3 = pb3;
            pb0 = pc0; pb1 = pc1; pb2 = pc2; pb3 = pc3;
            xa0 = xb0; xa1 = xb1; xa2 = xb2; xa3 = xb3;
        }
    }

    // Transposed LDS tile write: tA[feat][node].
    #pragma unroll
    for (int c = 0; c < 4; ++c) {
        tA[(4 * l4 + c) * TP + nIB] = ((const float*)&accA)[c];
        tB[(4 * l4 + c) * TP + nIB] = ((const float*)&accB)[c];
    }

    __syncthreads();

    // GEMM phase: 256 threads, dir = t>>7; per dir 128 threads cover
    // 16 nodes x 64 feats as 2 nodes x 4 feats per thread.
    int dir = t >> 7;
    int tx = t & 15;           // feat group: j4 = 4*tx
    int ty = (t >> 4) & 7;     // node pair:  n2 = 2*ty
    const float* W    = dir ? Wdst : Wsrc;
    const float* bias = dir ? bdst : bsrc;
    const float* tile = dir ? tB : tA;
    float* out        = dir ? outB : outA;
    int j4 = tx * 4, n2 = ty * 2;

    float4 bj = *(const float4*)&bias[j4];
    float4 a0 = bj, a1 = bj;
    #pragma unroll 8
    for (int k = 0; k < F; ++k) {
        float4 wv = *(const float4*)&W[k * F + j4];
        float2 v  = *(const float2*)&tile[k * TP + n2];   // 8B-aligned (TP even)
        a0.x += v.x * wv.x; a0.y += v.x * wv.y; a0.z += v.x * wv.z; a0.w += v.x * wv.w;
        a1.x += v.y * wv.x; a1.y += v.y * wv.y; a1.z += v.y * wv.z; a1.w += v.y * wv.w;
    }
    int nb = blockIdx.x * NPB + n2;
    *(float4*)&out[(size_t)(nb + 0) * F + j4] = a0;
    *(float4*)&out[(size_t)(nb + 1) * F + j4] = a1;
}

// ---------------- fallback path (round-1 atomic version) ----------------

__global__ __launch_bounds__(256) void scatter_fallback(const float4* __restrict__ x4,
                                                        const int* __restrict__ ei,
                                                        const float* __restrict__ ew,
                                                        float* __restrict__ aggA,
                                                        float* __restrict__ aggB) {
    int t = blockIdx.x * blockDim.x + threadIdx.x;
    int e = t >> 4;
    int lane16 = t & 15;
    if (e >= N_EDGES) return;
    int src = ei[e], dst = ei[N_EDGES + e];
    float w0 = ew[e], w1 = ew[N_EDGES + e];
    float4 v = x4[(size_t)src * 16 + lane16];
    int base = dst * F + lane16 * 4;
    atomicAdd(&aggA[base + 0], v.x * w0); atomicAdd(&aggA[base + 1], v.y * w0);
    atomicAdd(&aggA[base + 2], v.z * w0); atomicAdd(&aggA[base + 3], v.w * w0);
    atomicAdd(&aggB[base + 0], v.x * w1); atomicAdd(&aggB[base + 1], v.y * w1);
    atomicAdd(&aggB[base + 2], v.z * w1); atomicAdd(&aggB[base + 3], v.w * w1);
}

__global__ __launch_bounds__(256) void matmul_fallback(float* __restrict__ outA, float* __restrict__ outB,
                                                       const float* __restrict__ Wsrc, const float* __restrict__ Wdst,
                                                       const float* __restrict__ bsrc, const float* __restrict__ bdst) {
    __shared__ float lWs[F * F];
    __shared__ float lWd[F * F];
    for (int i = threadIdx.x; i < F * F / 4; i += blockDim.x) {
        ((float4*)lWs)[i] = ((const float4*)Wsrc)[i];
        ((float4*)lWd)[i] = ((const float4*)Wdst)[i];
    }
    __syncthreads();
    int wave = (blockIdx.x * blockDim.x + threadIdx.x) >> 6;
    int lane = threadIdx.x & 63;
    if (wave >= N_NODES) return;
    size_t rowbase = (size_t)wave * F;
    float a0 = outA[rowbase + lane], a1 = outB[rowbase + lane];
    float acc0 = bsrc[lane], acc1 = bdst[lane];
    #pragma unroll
    for (int k = 0; k < F; ++k) {
        acc0 += __shfl(a0, k) * lWs[k * F + lane];
        acc1 += __shfl(a1, k) * lWd[k * F + lane];
    }
    outA[rowbase + lane] = acc0;
    outB[rowbase + lane] = acc1;
}

// ---------------- launch ----------------

extern "C" void kernel_launch(void* const* d_in, const int* in_sizes, int n_in,
                              void* d_out, int out_size, void* d_ws, size_t ws_size,
                              hipStream_t stream) {
    const float* x    = (const float*)d_in[0];
    const int*   ei   = (const int*)d_in[1];
    const float* ew   = (const float*)d_in[2];
    const float* Wsrc = (const float*)d_in[3];
    const float* Wdst = (const float*)d_in[4];
    const float* bsrc = (const float*)d_in[5];
    const float* bdst = (const float*)d_in[6];

    float* outA = (float*)d_out;
    float* outB = (float*)d_out + (size_t)N_NODES * F;

    // ws layout. xh (12.8MB) OVERLAPS counts/partials/rank: those are dead
    // before cvt_kernel runs (hist->scan->permute complete first).
    const size_t OFF_XH       = 0;          // N*F*2 = 12,800,000 -> pad 12,800,256
    const size_t OFF_COUNTS   = 0;          // N*4 = 400,000 -> pad 400,128 (in xh region)
    const size_t OFF_PARTIALS = 400128;     // 512                (in xh region)
    const size_t OFF_RANK     = 400640;     // E*4 = 5,000,000    (in xh region)
    const size_t OFF_OFF      = 12800256;   // (N+1)*4 -> pad 400,512  (LIVE in agg)
    const size_t OFF_PAY      = 13200768;   // E*8 = 10,000,000        (LIVE in agg)
    const size_t REQ          = 23200768;

    if (ws_size >= REQ) {
        char* ws = (char*)d_ws;
        int*    counts   = (int*)(ws + OFF_COUNTS);
        int*    partials = (int*)(ws + OFF_PARTIALS);
        int*    rank     = (int*)(ws + OFF_RANK);
        int*    off      = (int*)(ws + OFF_OFF);
        int2*   pay      = (int2*)(ws + OFF_PAY);
        __half* xh       = (__half*)(ws + OFF_XH);

        hipMemsetAsync(counts, 0, (size_t)N_NODES * sizeof(int), stream);

        int eblk = (N_EDGES + 255) / 256;  // 4883
        hist_kernel<<<eblk, 256, 0, stream>>>(ei, counts, rank);
        scan_reduce_kernel<<<NBLK_SCAN, 256, 0, stream>>>(counts, partials);
        scan_apply_kernel<<<NBLK_SCAN, 256, 0, stream>>>(counts, partials, off);
        permute_kernel<<<eblk, 256, 0, stream>>>(ei, ew, off, rank, pay);
        // counts/partials/rank now dead -> xh may overwrite them.
        int cblk = (N_NODES * F / 4 + 255) / 256;  // 6250
        cvt_kernel<<<cblk, 256, 0, stream>>>(x, xh);
        agg_gemm_kernel<<<N_NODES / NPB, 256, 0, stream>>>(
            xh, off, pay, Wsrc, Wdst, bsrc, bdst, outA, outB);
    } else {
        hipMemsetAsync(d_out, 0, (size_t)out_size * sizeof(float), stream);
        int blocks_scatter = (N_EDGES * 16 + 255) / 256;
        scatter_fallback<<<blocks_scatter, 256, 0, stream>>>((const float4*)x, ei, ew, outA, outB);
        int blocks_mm = (N_NODES * 64 + 255) / 256;
        matmul_fallback<<<blocks_mm, 256, 0, stream>>>(outA, outB, Wsrc, Wdst, bsrc, bdst);
    }
}

// Round 18
// 253.577 us; speedup vs baseline: 1.0356x; 1.0356x over previous
//
#include <hip/hip_runtime.h>
#include <hip/hip_fp16.h>

#define N_NODES 100000
#define N_EDGES 1250000
#define F 64
#define SCAN_CHUNK 1024
#define NBLK_SCAN ((N_NODES + SCAN_CHUNK - 1) / SCAN_CHUNK)  // 98
#define NPB 16   // nodes per block: 4 waves x 4 groups(16 lanes) = 16 nodes
#define TP 18    // tile leading pad: keeps (k*TP+n)*4 8B-aligned for float2 reads
#define PAY_PAD 12  // zeroed tail entries -> prefetch needs no index clamps

// ---------------- CSR-build path ----------------

// K1: histogram of receivers + per-edge rank within receiver.
// The atomic return value IS the rank -> permute needs no atomic at all.
__global__ __launch_bounds__(256) void hist_kernel(const int* __restrict__ ei,
                                                   int* __restrict__ counts,
                                                   int* __restrict__ rank) {
    int e = blockIdx.x * 256 + threadIdx.x;
    if (e < N_EDGES) rank[e] = atomicAdd(&counts[ei[N_EDGES + e]], 1);
}

// K2a: per-1024-chunk partial sums of counts.
__global__ __launch_bounds__(256) void scan_reduce_kernel(const int* __restrict__ counts,
                                                          int* __restrict__ partials) {
    int base = blockIdx.x * SCAN_CHUNK + threadIdx.x * 4;
    int s = 0;
    if (base + 3 < N_NODES) {
        int4 c = *(const int4*)&counts[base];
        s = c.x + c.y + c.z + c.w;
    }
    for (int d = 32; d > 0; d >>= 1) s += __shfl_down(s, d);
    __shared__ int lds[4];
    int lane = threadIdx.x & 63, wave = threadIdx.x >> 6;
    if (lane == 0) lds[wave] = s;
    __syncthreads();
    if (threadIdx.x == 0) partials[blockIdx.x] = lds[0] + lds[1] + lds[2] + lds[3];
}

// K2b: per-chunk exclusive scan; chunk base reduced in-block from raw partials.
__global__ __launch_bounds__(256) void scan_apply_kernel(const int* __restrict__ counts,
                                                         const int* __restrict__ partials,
                                                         int* __restrict__ off) {
    __shared__ int sh_red[4];
    __shared__ int sh_base;
    __shared__ int wsum[4];
    int t = threadIdx.x;
    int lane = t & 63, wave = t >> 6;

    int pp = 0;
    if (t < blockIdx.x && t < NBLK_SCAN) pp = partials[t];
    for (int d = 32; d > 0; d >>= 1) pp += __shfl_down(pp, d);
    if (lane == 0) sh_red[wave] = pp;
    __syncthreads();
    if (t == 0) sh_base = sh_red[0] + sh_red[1] + sh_red[2] + sh_red[3];

    int base = blockIdx.x * SCAN_CHUNK + t * 4;
    int4 c = {0, 0, 0, 0};
    bool act = (base + 3 < N_NODES);
    if (act) c = *(const int4*)&counts[base];
    int s = c.x + c.y + c.z + c.w;

    int xs = s;
    for (int d = 1; d < 64; d <<= 1) {
        int y = __shfl_up(xs, d);
        if (lane >= d) xs += y;
    }
    if (lane == 63) wsum[wave] = xs;
    __syncthreads();
    int pre = xs - s;
    for (int w = 0; w < wave; ++w) pre += wsum[w];
    pre += sh_base;

    if (act) {
        int o0 = pre, o1 = o0 + c.x, o2 = o1 + c.y, o3 = o2 + c.z;
        int4 o = {o0, o1, o2, o3};
        *(int4*)&off[base] = o;
        if (base + 4 == N_NODES) off[N_NODES] = o3 + c.w;  // == N_EDGES
    }
}

// K3: scatter packed payload {src:int, (w0,w1):half2} -> ONE 8B store per edge.
// Atomic-free: pos = off[r] + rank[e].
__global__ __launch_bounds__(256) void permute_kernel(const int* __restrict__ ei,
                                                      const float* __restrict__ ew,
                                                      const int* __restrict__ off,
                                                      const int* __restrict__ rank,
                                                      int2* __restrict__ pay) {
    int e = blockIdx.x * 256 + threadIdx.x;
    if (e >= N_EDGES) return;
    int r = ei[N_EDGES + e];
    int pos = off[r] + rank[e];
    __half2 h = __floats2half2_rn(ew[e], ew[N_EDGES + e]);
    int2 p;
    p.x = ei[e];
    p.y = *(const int*)&h;
    pay[pos] = p;
}

// K3b: x (fp32) -> xh (fp16). Streaming, vectorized. Halves the random-gather
// line count in K4: one 128B line per edge row instead of two.
__global__ __launch_bounds__(256) void cvt_kernel(const float* __restrict__ x,
                                                  __half* __restrict__ xh) {
    int i = blockIdx.x * 256 + threadIdx.x;
    int base = i * 4;
    if (base < N_NODES * F) {
        float4 v = *(const float4*)&x[base];
        __half2 h0 = __floats2half2_rn(v.x, v.y);
        __half2 h1 = __floats2half2_rn(v.z, v.w);
        uint2 u;
        u.x = *(const unsigned int*)&h0;
        u.y = *(const unsigned int*)&h1;
        *(uint2*)&xh[base] = u;
    }
}

// K4: fused aggregation + GEMM. 256 threads = 4 waves x 4 groups of 16 lanes.
// Each 16-lane group owns ONE node; lane l4 holds features [4*l4,4*l4+4).
// fp16 x rows: a group's row read = 16 lanes x 8B = ONE 128B line.
// Pipeline: pay is loaded 2 batches ahead of the x-issue, x 1 batch ahead of
// use. pay is padded with PAY_PAD zeroed entries -> prefetch indices need no
// clamps (pad: weight 0, src 0 -> row-0 load, zero contribution). Cross-node
// edges inside the tail window are suppressed by the wv=0 guard.
// 8 blocks/CU (32 waves) for max memory-level parallelism on the gather.
__global__ __launch_bounds__(256, 8) void agg_gemm_kernel(
    const __half* __restrict__ xh, const int* __restrict__ off,
    const int2* __restrict__ pay,
    const float* __restrict__ Wsrc, const float* __restrict__ Wdst,
    const float* __restrict__ bsrc, const float* __restrict__ bdst,
    float* __restrict__ outA, float* __restrict__ outB)
{
    __shared__ float tA[F * TP];
    __shared__ float tB[F * TP];
    int t = threadIdx.x;
    int w = t >> 6;          // wave 0..3
    int lane = t & 63;
    int g = lane >> 4;       // group in wave 0..3
    int l4 = lane & 15;      // feat4 index 0..15
    int nIB = w * 4 + g;     // node in block 0..15
    int n = blockIdx.x * NPB + nIB;

    int beg = off[n];
    int end = off[n + 1];

    float4 accA = {0.f, 0.f, 0.f, 0.f};
    float4 accB = {0.f, 0.f, 0.f, 0.f};

    if (beg < end) {
        // pay batches A (edges i..i+3) and B (i+4..i+7), x batch for A.
        // No clamps: pay is padded by PAY_PAD >= 12 zeroed entries.
        int2 pa0 = pay[beg];
        int2 pa1 = pay[beg + 1];
        int2 pa2 = pay[beg + 2];
        int2 pa3 = pay[beg + 3];
        int2 pb0 = pay[beg + 4];
        int2 pb1 = pay[beg + 5];
        int2 pb2 = pay[beg + 6];
        int2 pb3 = pay[beg + 7];
        uint2 xa0 = *(const uint2*)(xh + (size_t)pa0.x * F + l4 * 4);
        uint2 xa1 = *(const uint2*)(xh + (size_t)pa1.x * F + l4 * 4);
        uint2 xa2 = *(const uint2*)(xh + (size_t)pa2.x * F + l4 * 4);
        uint2 xa3 = *(const uint2*)(xh + (size_t)pa3.x * F + l4 * 4);

        for (int i = beg; i < end; i += 4) {
            // pay batch C (i+8..i+11) -- 2 batches ahead
            int2 pc0 = pay[i + 8];
            int2 pc1 = pay[i + 9];
            int2 pc2 = pay[i + 10];
            int2 pc3 = pay[i + 11];
            // x batch B -- addresses from pay loaded last iteration
            uint2 xb0 = *(const uint2*)(xh + (size_t)pb0.x * F + l4 * 4);
            uint2 xb1 = *(const uint2*)(xh + (size_t)pb1.x * F + l4 * 4);
            uint2 xb2 = *(const uint2*)(xh + (size_t)pb2.x * F + l4 * 4);
            uint2 xb3 = *(const uint2*)(xh + (size_t)pb3.x * F + l4 * 4);

            // FMA batch A (x loaded last iteration); zero weight for OOB tail.
#define EDGE(J, PJ, XJ)                                                   \
            {                                                             \
                float2 wv = __half22float2(*(const __half2*)&PJ.y);       \
                if (i + J >= end) { wv.x = 0.f; wv.y = 0.f; }             \
                float2 lo = __half22float2(*(const __half2*)&XJ.x);       \
                float2 hi = __half22float2(*(const __half2*)&XJ.y);       \
                accA.x += lo.x * wv.x; accA.y += lo.y * wv.x;             \
                accA.z += hi.x * wv.x; accA.w += hi.y * wv.x;             \
                accB.x += lo.x * wv.y; accB.y += lo.y * wv.y;             \
                accB.z += hi.x * wv.y; accB.w += hi.y * wv.y;             \
            }
            EDGE(0, pa0, xa0)
            EDGE(1, pa1, xa1)
            EDGE(2, pa2, xa2)
            EDGE(3, pa3, xa3)
#undef EDGE
            // shift pipeline
            pa0 = pb0; pa1 = pb1; pa2 = pb2; pa3 = pb3;
            pb0 = pc0; pb1 = pc1; pb2 = pc2; pb3 = pc3;
            xa0 = xb0; xa1 = xb1; xa2 = xb2; xa3 = xb3;
        }
    }

    // Transposed LDS tile write: tA[feat][node].
    #pragma unroll
    for (int c = 0; c < 4; ++c) {
        tA[(4 * l4 + c) * TP + nIB] = ((const float*)&accA)[c];
        tB[(4 * l4 + c) * TP + nIB] = ((const float*)&accB)[c];
    }

    __syncthreads();

    // GEMM phase: 256 threads, dir = t>>7; per dir 128 threads cover
    // 16 nodes x 64 feats as 2 nodes x 4 feats per thread.
    int dir = t >> 7;
    int tx = t & 15;           // feat group: j4 = 4*tx
    int ty = (t >> 4) & 7;     // node pair:  n2 = 2*ty
    const float* W    = dir ? Wdst : Wsrc;
    const float* bias = dir ? bdst : bsrc;
    const float* tile = dir ? tB : tA;
    float* out        = dir ? outB : outA;
    int j4 = tx * 4, n2 = ty * 2;

    float4 bj = *(const float4*)&bias[j4];
    float4 a0 = bj, a1 = bj;
    #pragma unroll 8
    for (int k = 0; k < F; ++k) {
        float4 wv = *(const float4*)&W[k * F + j4];
        float2 v  = *(const float2*)&tile[k * TP + n2];   // 8B-aligned (TP even)
        a0.x += v.x * wv.x; a0.y += v.x * wv.y; a0.z += v.x * wv.z; a0.w += v.x * wv.w;
        a1.x += v.y * wv.x; a1.y += v.y * wv.y; a1.z += v.y * wv.z; a1.w += v.y * wv.w;
    }
    int nb = blockIdx.x * NPB + n2;
    *(float4*)&out[(size_t)(nb + 0) * F + j4] = a0;
    *(float4*)&out[(size_t)(nb + 1) * F + j4] = a1;
}

// ---------------- fallback path (round-1 atomic version) ----------------

__global__ __launch_bounds__(256) void scatter_fallback(const float4* __restrict__ x4,
                                                        const int* __restrict__ ei,
                                                        const float* __restrict__ ew,
                                                        float* __restrict__ aggA,
                                                        float* __restrict__ aggB) {
    int t = blockIdx.x * blockDim.x + threadIdx.x;
    int e = t >> 4;
    int lane16 = t & 15;
    if (e >= N_EDGES) return;
    int src = ei[e], dst = ei[N_EDGES + e];
    float w0 = ew[e], w1 = ew[N_EDGES + e];
    float4 v = x4[(size_t)src * 16 + lane16];
    int base = dst * F + lane16 * 4;
    atomicAdd(&aggA[base + 0], v.x * w0); atomicAdd(&aggA[base + 1], v.y * w0);
    atomicAdd(&aggA[base + 2], v.z * w0); atomicAdd(&aggA[base + 3], v.w * w0);
    atomicAdd(&aggB[base + 0], v.x * w1); atomicAdd(&aggB[base + 1], v.y * w1);
    atomicAdd(&aggB[base + 2], v.z * w1); atomicAdd(&aggB[base + 3], v.w * w1);
}

__global__ __launch_bounds__(256) void matmul_fallback(float* __restrict__ outA, float* __restrict__ outB,
                                                       const float* __restrict__ Wsrc, const float* __restrict__ Wdst,
                                                       const float* __restrict__ bsrc, const float* __restrict__ bdst) {
    __shared__ float lWs[F * F];
    __shared__ float lWd[F * F];
    for (int i = threadIdx.x; i < F * F / 4; i += blockDim.x) {
        ((float4*)lWs)[i] = ((const float4*)Wsrc)[i];
        ((float4*)lWd)[i] = ((const float4*)Wdst)[i];
    }
    __syncthreads();
    int wave = (blockIdx.x * blockDim.x + threadIdx.x) >> 6;
    int lane = threadIdx.x & 63;
    if (wave >= N_NODES) return;
    size_t rowbase = (size_t)wave * F;
    float a0 = outA[rowbase + lane], a1 = outB[rowbase + lane];
    float acc0 = bsrc[lane], acc1 = bdst[lane];
    #pragma unroll
    for (int k = 0; k < F; ++k) {
        acc0 += __shfl(a0, k) * lWs[k * F + lane];
        acc1 += __shfl(a1, k) * lWd[k * F + lane];
    }
    outA[rowbase + lane] = acc0;
    outB[rowbase + lane] = acc1;
}

// ---------------- launch ----------------

extern "C" void kernel_launch(void* const* d_in, const int* in_sizes, int n_in,
                              void* d_out, int out_size, void* d_ws, size_t ws_size,
                              hipStream_t stream) {
    const float* x    = (const float*)d_in[0];
    const int*   ei   = (const int*)d_in[1];
    const float* ew   = (const float*)d_in[2];
    const float* Wsrc = (const float*)d_in[3];
    const float* Wdst = (const float*)d_in[4];
    const float* bsrc = (const float*)d_in[5];
    const float* bdst = (const float*)d_in[6];

    float* outA = (float*)d_out;
    float* outB = (float*)d_out + (size_t)N_NODES * F;

    // ws layout. xh (12.8MB) OVERLAPS counts/partials/rank: those are dead
    // before cvt_kernel runs (hist->scan->permute complete first).
    const size_t OFF_XH       = 0;          // N*F*2 = 12,800,000 -> pad 12,800,256
    const size_t OFF_COUNTS   = 0;          // N*4 = 400,000 -> pad 400,128 (in xh region)
    const size_t OFF_PARTIALS = 400128;     // 512                (in xh region)
    const size_t OFF_RANK     = 400640;     // E*4 = 5,000,000    (in xh region)
    const size_t OFF_OFF      = 12800256;   // (N+1)*4 -> pad 400,512  (LIVE in agg)
    const size_t OFF_PAY      = 13200768;   // (E+PAY_PAD)*8 = 10,000,096 (LIVE in agg)
    const size_t REQ          = 23200864;

    if (ws_size >= REQ) {
        char* ws = (char*)d_ws;
        int*    counts   = (int*)(ws + OFF_COUNTS);
        int*    partials = (int*)(ws + OFF_PARTIALS);
        int*    rank     = (int*)(ws + OFF_RANK);
        int*    off      = (int*)(ws + OFF_OFF);
        int2*   pay      = (int2*)(ws + OFF_PAY);
        __half* xh       = (__half*)(ws + OFF_XH);

        hipMemsetAsync(counts, 0, (size_t)N_NODES * sizeof(int), stream);
        // zero the pay pad once: prefetch reads land here with weight 0, src 0
        hipMemsetAsync(pay + N_EDGES, 0, PAY_PAD * sizeof(int2), stream);

        int eblk = (N_EDGES + 255) / 256;  // 4883
        hist_kernel<<<eblk, 256, 0, stream>>>(ei, counts, rank);
        scan_reduce_kernel<<<NBLK_SCAN, 256, 0, stream>>>(counts, partials);
        scan_apply_kernel<<<NBLK_SCAN, 256, 0, stream>>>(counts, partials, off);
        permute_kernel<<<eblk, 256, 0, stream>>>(ei, ew, off, rank, pay);
        // counts/partials/rank now dead -> xh may overwrite them.
        int cblk = (N_NODES * F / 4 + 255) / 256;  // 6250
        cvt_kernel<<<cblk, 256, 0, stream>>>(x, xh);
        agg_gemm_kernel<<<N_NODES / NPB, 256, 0, stream>>>(
            xh, off, pay, Wsrc, Wdst, bsrc, bdst, outA, outB);
    } else {
        hipMemsetAsync(d_out, 0, (size_t)out_size * sizeof(float), stream);
        int blocks_scatter = (N_EDGES * 16 + 255) / 256;
        scatter_fallback<<<blocks_scatter, 256, 0, stream>>>((const float4*)x, ei, ew, outA, outB);
        int blocks_mm = (N_NODES * 64 + 255) / 256;
        matmul_fallback<<<blocks_mm, 256, 0, stream>>>(outA, outB, Wsrc, Wdst, bsrc, bdst);
    }
}

// Round 19
// 219.036 us; speedup vs baseline: 1.1989x; 1.1577x over previous
//
#include <hip/hip_runtime.h>
#include <hip/hip_fp16.h>

#define N_NODES 100000
#define N_EDGES 1250000
#define F 64
#define NPB 16   // nodes per block in agg: 4 waves x 4 groups(16 lanes)
#define TP 18    // tile leading pad
#define PAY_PAD 12
#define NB 256          // coarse buckets
#define NPBK 391        // nodes per bucket: 256*391 = 100096 >= N_NODES
#define BCAP 6144       // per-bucket tmp capacity (mean 4883, +18 sigma)

// ---------------- two-level bucket-sort CSR build ----------------

__global__ __launch_bounds__(256) void init_cursor_kernel(int* __restrict__ cursor) {
    int b = threadIdx.x;
    if (b < NB) cursor[b] = b * BCAP;
}

// Pass A: bin edges into 256 coarse buckets. Packed entry:
//   .x = (src << 9) | local_r   (src<=99999 -> 17 bits; local_r<391 -> 9 bits)
//   .y = half2(w0, w1)
__global__ __launch_bounds__(1024) void bucket_kernel(const int* __restrict__ ei,
                                                      const float* __restrict__ ew,
                                                      int* __restrict__ cursor,
                                                      int2* __restrict__ tmp) {
    __shared__ int lh[NB];
    __shared__ int bb[NB];
    __shared__ int lc[NB];
    int t = threadIdx.x;
    int e = blockIdx.x * 1024 + t;
    if (t < NB) { lh[t] = 0; lc[t] = 0; }
    __syncthreads();
    int r = 0, src = 0, bkt = -1;
    float w0 = 0.f, w1 = 0.f;
    if (e < N_EDGES) {
        r = ei[N_EDGES + e];
        src = ei[e];
        w0 = ew[e];
        w1 = ew[N_EDGES + e];
        bkt = r / NPBK;
        atomicAdd(&lh[bkt], 1);
    }
    __syncthreads();
    if (t < NB && lh[t] > 0) bb[t] = atomicAdd(&cursor[t], lh[t]);
    __syncthreads();
    if (e < N_EDGES) {
        int lr = atomicAdd(&lc[bkt], 1);
        int pos = bb[bkt] + lr;
        __half2 h = __floats2half2_rn(w0, w1);
        int lrr = r - bkt * NPBK;   // 0..390
        int2 p;
        p.x = (src << 9) | lrr;
        p.y = *(const int*)&h;
        tmp[pos] = p;
    }
}

// Pass B: one block per bucket. LDS hist over 391 local nodes + LDS scan ->
// writes off[] and scatters pay within the bucket's contiguous (L2-resident)
// output region. No global atomics; scattered 8B stores are absorbed by L2
// and written back as full lines.
__global__ __launch_bounds__(512) void scatter_kernel(const int* __restrict__ cursor,
                                                      const int2* __restrict__ tmp,
                                                      int* __restrict__ off,
                                                      int2* __restrict__ pay) {
    __shared__ int lh[NPBK];
    __shared__ int loff[NPBK];
    __shared__ int lc[NPBK];
    __shared__ int sc[NB];
    __shared__ int sh_base;
    int t = threadIdx.x;
    int bkt = blockIdx.x;

    if (t < NB) sc[t] = cursor[t] - t * BCAP;   // bucket counts
    for (int j = t; j < NPBK; j += 512) { lh[j] = 0; lc[j] = 0; }
    __syncthreads();
    if (t == 0) {
        int s = 0;
        for (int j = 0; j < bkt; ++j) s += sc[j];
        sh_base = s;
    }
    __syncthreads();
    int base_g = sh_base;
    int cnt = sc[bkt];
    const int2* te = tmp + (size_t)bkt * BCAP;

    // local histogram
    for (int i = t; i < cnt; i += 512) {
        int lrr = te[i].x & 511;
        atomicAdd(&lh[lrr], 1);
    }
    __syncthreads();
    // inclusive Hillis-Steele scan of lh into loff (each thread owns <=1 bin)
    if (t < NPBK) loff[t] = lh[t];
    __syncthreads();
    for (int d = 1; d < NPBK; d <<= 1) {
        int v = 0;
        if (t < NPBK && t >= d) v = loff[t - d];
        __syncthreads();
        if (t < NPBK && t >= d) loff[t] += v;
        __syncthreads();
    }
    // off[] for agg (exclusive = inclusive - count)
    if (t < NPBK) {
        int node = bkt * NPBK + t;
        if (node < N_NODES) off[node] = base_g + loff[t] - lh[t];
    }
    if (bkt == 0 && t == 0) off[N_NODES] = N_EDGES;
    __syncthreads();
    // scatter into pay (bucket-contiguous region)
    for (int i = t; i < cnt; i += 512) {
        int2 p = te[i];
        int lrr = p.x & 511;
        int lr = atomicAdd(&lc[lrr], 1);
        int pos = base_g + (loff[lrr] - lh[lrr]) + lr;
        int2 o;
        o.x = p.x >> 9;   // src
        o.y = p.y;        // half2 weights
        pay[pos] = o;
    }
}

// K3b: x (fp32) -> xh (fp16). Runs AFTER scatter_kernel (xh overlays tmp).
__global__ __launch_bounds__(256) void cvt_kernel(const float* __restrict__ x,
                                                  __half* __restrict__ xh) {
    int i = blockIdx.x * 256 + threadIdx.x;
    int base = i * 4;
    if (base < N_NODES * F) {
        float4 v = *(const float4*)&x[base];
        __half2 h0 = __floats2half2_rn(v.x, v.y);
        __half2 h1 = __floats2half2_rn(v.z, v.w);
        uint2 u;
        u.x = *(const unsigned int*)&h0;
        u.y = *(const unsigned int*)&h1;
        *(uint2*)&xh[base] = u;
    }
}

// K4: fused aggregation + GEMM (unchanged from round 18).
__global__ __launch_bounds__(256, 8) void agg_gemm_kernel(
    const __half* __restrict__ xh, const int* __restrict__ off,
    const int2* __restrict__ pay,
    const float* __restrict__ Wsrc, const float* __restrict__ Wdst,
    const float* __restrict__ bsrc, const float* __restrict__ bdst,
    float* __restrict__ outA, float* __restrict__ outB)
{
    __shared__ float tA[F * TP];
    __shared__ float tB[F * TP];
    int t = threadIdx.x;
    int w = t >> 6;
    int lane = t & 63;
    int g = lane >> 4;
    int l4 = lane & 15;
    int nIB = w * 4 + g;
    int n = blockIdx.x * NPB + nIB;

    int beg = off[n];
    int end = off[n + 1];

    float4 accA = {0.f, 0.f, 0.f, 0.f};
    float4 accB = {0.f, 0.f, 0.f, 0.f};

    if (beg < end) {
        int2 pa0 = pay[beg];
        int2 pa1 = pay[beg + 1];
        int2 pa2 = pay[beg + 2];
        int2 pa3 = pay[beg + 3];
        int2 pb0 = pay[beg + 4];
        int2 pb1 = pay[beg + 5];
        int2 pb2 = pay[beg + 6];
        int2 pb3 = pay[beg + 7];
        uint2 xa0 = *(const uint2*)(xh + (size_t)pa0.x * F + l4 * 4);
        uint2 xa1 = *(const uint2*)(xh + (size_t)pa1.x * F + l4 * 4);
        uint2 xa2 = *(const uint2*)(xh + (size_t)pa2.x * F + l4 * 4);
        uint2 xa3 = *(const uint2*)(xh + (size_t)pa3.x * F + l4 * 4);

        for (int i = beg; i < end; i += 4) {
            int2 pc0 = pay[i + 8];
            int2 pc1 = pay[i + 9];
            int2 pc2 = pay[i + 10];
            int2 pc3 = pay[i + 11];
            uint2 xb0 = *(const uint2*)(xh + (size_t)pb0.x * F + l4 * 4);
            uint2 xb1 = *(const uint2*)(xh + (size_t)pb1.x * F + l4 * 4);
            uint2 xb2 = *(const uint2*)(xh + (size_t)pb2.x * F + l4 * 4);
            uint2 xb3 = *(const uint2*)(xh + (size_t)pb3.x * F + l4 * 4);

#define EDGE(J, PJ, XJ)                                                   \
            {                                                             \
                float2 wv = __half22float2(*(const __half2*)&PJ.y);       \
                if (i + J >= end) { wv.x = 0.f; wv.y = 0.f; }             \
                float2 lo = __half22float2(*(const __half2*)&XJ.x);       \
                float2 hi = __half22float2(*(const __half2*)&XJ.y);       \
                accA.x += lo.x * wv.x; accA.y += lo.y * wv.x;             \
                accA.z += hi.x * wv.x; accA.w += hi.y * wv.x;             \
                accB.x += lo.x * wv.y; accB.y += lo.y * wv.y;             \
                accB.z += hi.x * wv.y; accB.w += hi.y * wv.y;             \
            }
            EDGE(0, pa0, xa0)
            EDGE(1, pa1, xa1)
            EDGE(2, pa2, xa2)
            EDGE(3, pa3, xa3)
#undef EDGE
            pa0 = pb0; pa1 = pb1; pa2 = pb2; pa3 = pb3;
            pb0 = pc0; pb1 = pc1; pb2 = pc2; pb3 = pc3;
            xa0 = xb0; xa1 = xb1; xa2 = xb2; xa3 = xb3;
        }
    }

    #pragma unroll
    for (int c = 0; c < 4; ++c) {
        tA[(4 * l4 + c) * TP + nIB] = ((const float*)&accA)[c];
        tB[(4 * l4 + c) * TP + nIB] = ((const float*)&accB)[c];
    }

    __syncthreads();

    int dir = t >> 7;
    int tx = t & 15;
    int ty = (t >> 4) & 7;
    const float* W    = dir ? Wdst : Wsrc;
    const float* bias = dir ? bdst : bsrc;
    const float* tile = dir ? tB : tA;
    float* out        = dir ? outB : outA;
    int j4 = tx * 4, n2 = ty * 2;

    float4 bj = *(const float4*)&bias[j4];
    float4 a0 = bj, a1 = bj;
    #pragma unroll 8
    for (int k = 0; k < F; ++k) {
        float4 wv = *(const float4*)&W[k * F + j4];
        float2 v  = *(const float2*)&tile[k * TP + n2];
        a0.x += v.x * wv.x; a0.y += v.x * wv.y; a0.z += v.x * wv.z; a0.w += v.x * wv.w;
        a1.x += v.y * wv.x; a1.y += v.y * wv.y; a1.z += v.y * wv.z; a1.w += v.y * wv.w;
    }
    int nb = blockIdx.x * NPB + n2;
    *(float4*)&out[(size_t)(nb + 0) * F + j4] = a0;
    *(float4*)&out[(size_t)(nb + 1) * F + j4] = a1;
}

// ---------------- fallback path (round-1 atomic version) ----------------

__global__ __launch_bounds__(256) void scatter_fallback(const float4* __restrict__ x4,
                                                        const int* __restrict__ ei,
                                                        const float* __restrict__ ew,
                                                        float* __restrict__ aggA,
                                                        float* __restrict__ aggB) {
    int t = blockIdx.x * blockDim.x + threadIdx.x;
    int e = t >> 4;
    int lane16 = t & 15;
    if (e >= N_EDGES) return;
    int src = ei[e], dst = ei[N_EDGES + e];
    float w0 = ew[e], w1 = ew[N_EDGES + e];
    float4 v = x4[(size_t)src * 16 + lane16];
    int base = dst * F + lane16 * 4;
    atomicAdd(&aggA[base + 0], v.x * w0); atomicAdd(&aggA[base + 1], v.y * w0);
    atomicAdd(&aggA[base + 2], v.z * w0); atomicAdd(&aggA[base + 3], v.w * w0);
    atomicAdd(&aggB[base + 0], v.x * w1); atomicAdd(&aggB[base + 1], v.y * w1);
    atomicAdd(&aggB[base + 2], v.z * w1); atomicAdd(&aggB[base + 3], v.w * w1);
}

__global__ __launch_bounds__(256) void matmul_fallback(float* __restrict__ outA, float* __restrict__ outB,
                                                       const float* __restrict__ Wsrc, const float* __restrict__ Wdst,
                                                       const float* __restrict__ bsrc, const float* __restrict__ bdst) {
    __shared__ float lWs[F * F];
    __shared__ float lWd[F * F];
    for (int i = threadIdx.x; i < F * F / 4; i += blockDim.x) {
        ((float4*)lWs)[i] = ((const float4*)Wsrc)[i];
        ((float4*)lWd)[i] = ((const float4*)Wdst)[i];
    }
    __syncthreads();
    int wave = (blockIdx.x * blockDim.x + threadIdx.x) >> 6;
    int lane = threadIdx.x & 63;
    if (wave >= N_NODES) return;
    size_t rowbase = (size_t)wave * F;
    float a0 = outA[rowbase + lane], a1 = outB[rowbase + lane];
    float acc0 = bsrc[lane], acc1 = bdst[lane];
    #pragma unroll
    for (int k = 0; k < F; ++k) {
        acc0 += __shfl(a0, k) * lWs[k * F + lane];
        acc1 += __shfl(a1, k) * lWd[k * F + lane];
    }
    outA[rowbase + lane] = acc0;
    outB[rowbase + lane] = acc1;
}

// ---------------- launch ----------------

extern "C" void kernel_launch(void* const* d_in, const int* in_sizes, int n_in,
                              void* d_out, int out_size, void* d_ws, size_t ws_size,
                              hipStream_t stream) {
    const float* x    = (const float*)d_in[0];
    const int*   ei   = (const int*)d_in[1];
    const float* ew   = (const float*)d_in[2];
    const float* Wsrc = (const float*)d_in[3];
    const float* Wdst = (const float*)d_in[4];
    const float* bsrc = (const float*)d_in[5];
    const float* bdst = (const float*)d_in[6];

    float* outA = (float*)d_out;
    float* outB = (float*)d_out + (size_t)N_NODES * F;

    // ws layout. tmp (12.58MB) overlays xh (12.8MB): tmp dead before cvt runs.
    const size_t OFF_TMP    = 0;          // NB*BCAP*8 = 12,582,912
    const size_t OFF_XH     = 0;          // N*F*2 = 12,800,000 -> pad 12,800,256
    const size_t OFF_CURSOR = 12800256;   // NB*4 = 1024 -> pad 12,801,280
    const size_t OFF_OFF    = 12801280;   // (N+1)*4 = 400,004 -> pad 13,201,792
    const size_t OFF_PAY    = 13201792;   // (E+PAY_PAD)*8 = 10,000,096
    const size_t REQ        = 23201888;

    if (ws_size >= REQ) {
        char* ws = (char*)d_ws;
        int2*   tmp    = (int2*)(ws + OFF_TMP);
        __half* xh     = (__half*)(ws + OFF_XH);
        int*    cursor = (int*)(ws + OFF_CURSOR);
        int*    off    = (int*)(ws + OFF_OFF);
        int2*   pay    = (int2*)(ws + OFF_PAY);

        // zero the pay pad (prefetch tail reads: weight 0, src 0)
        hipMemsetAsync(pay + N_EDGES, 0, PAY_PAD * sizeof(int2), stream);

        init_cursor_kernel<<<1, 256, 0, stream>>>(cursor);
        int ablk = (N_EDGES + 1023) / 1024;  // 1221
        bucket_kernel<<<ablk, 1024, 0, stream>>>(ei, ew, cursor, tmp);
        scatter_kernel<<<NB, 512, 0, stream>>>(cursor, tmp, off, pay);
        // tmp dead -> xh may overwrite it.
        int cblk = (N_NODES * F / 4 + 255) / 256;  // 6250
        cvt_kernel<<<cblk, 256, 0, stream>>>(x, xh);
        agg_gemm_kernel<<<N_NODES / NPB, 256, 0, stream>>>(
            xh, off, pay, Wsrc, Wdst, bsrc, bdst, outA, outB);
    } else {
        hipMemsetAsync(d_out, 0, (size_t)out_size * sizeof(float), stream);
        int blocks_scatter = (N_EDGES * 16 + 255) / 256;
        scatter_fallback<<<blocks_scatter, 256, 0, stream>>>((const float4*)x, ei, ew, outA, outB);
        int blocks_mm = (N_NODES * 64 + 255) / 256;
        matmul_fallback<<<blocks_mm, 256, 0, stream>>>(outA, outB, Wsrc, Wdst, bsrc, bdst);
    }
}